// Round 8
// baseline (1427.317 us; speedup 1.0000x reference)
//
#include <hip/hip_runtime.h>
#include <math.h>

#define HID 32
#define BS 256

// ---- bucketed counting-sort parameters (q-space buckets) ----
#define NPB 2048          // nodes per bucket
#define NBK_MAX 1024      // LDS sizing cap for bucket count
#define EBT 8192          // edges per scatter tile
#define CAP 30720         // per-bucket LDS srt capacity (max window ~= 2048*max_deg_in_window)

// ---------------- degree + permutation ----------------

// deg[dst]++ over M edges (original node space)
__global__ void k_count(const int* __restrict__ ei, int* __restrict__ deg, int M) {
  int e = blockIdx.x * BS + threadIdx.x;
  if (e < M) atomicAdd(&deg[ei[M + e]], 1);
}

// 16-bin global histogram of min(deg,15)
__global__ void k_dhist16(const int* __restrict__ deg, int* __restrict__ dh, int T) {
  __shared__ int h[16];
  if (threadIdx.x < 16) h[threadIdx.x] = 0;
  __syncthreads();
  int i = blockIdx.x * BS + threadIdx.x;
  if (i < T) atomicAdd(&h[min(deg[i], 15)], 1);
  __syncthreads();
  if (threadIdx.x < 16 && h[threadIdx.x]) atomicAdd(&dh[threadIdx.x], h[threadIdx.x]);
}

// exclusive scan of 16 bins -> global bin cursors
__global__ void k_dscan16(const int* __restrict__ dh, int* __restrict__ dcur) {
  if (threadIdx.x == 0) {
    int run = 0;
    for (int b = 0; b < 16; ++b) { dcur[b] = run; run += dh[b]; }
  }
}

// per-block: reserve a run per bin, assign q = permuted index; perminv[i] = q
__global__ __launch_bounds__(BS) void k_dperm(const int* __restrict__ deg,
                                              int* __restrict__ dcur,
                                              int* __restrict__ perminv, int T) {
  __shared__ int lhist[16];
  __shared__ int lcur[16];
  if (threadIdx.x < 16) lhist[threadIdx.x] = 0;
  __syncthreads();
  int i = blockIdx.x * BS + threadIdx.x;
  int b = -1;
  if (i < T) {
    b = min(deg[i], 15);
    atomicAdd(&lhist[b], 1);
  }
  __syncthreads();
  if (threadIdx.x < 16)
    lcur[threadIdx.x] = lhist[threadIdx.x] ? atomicAdd(&dcur[threadIdx.x], lhist[threadIdx.x]) : 0;
  __syncthreads();
  if (i < T) {
    int q = atomicAdd(&lcur[b], 1);
    perminv[i] = q;
  }
}

// ---------------- bucketed sort (q-space dst) ----------------

__global__ __launch_bounds__(BS) void k_bhist(const int* __restrict__ ei,
                                              const int* __restrict__ perminv,
                                              int* __restrict__ gh, int M, int NBK) {
  __shared__ int hist[NBK_MAX];
  for (int b = threadIdx.x; b < NBK; b += BS) hist[b] = 0;
  __syncthreads();
  int e0 = blockIdx.x * EBT;
  int n = min(EBT, M - e0);
  for (int k = threadIdx.x; k < n; k += BS) {
    int pd = perminv[ei[M + e0 + k]];
    atomicAdd(&hist[pd / NPB], 1);
  }
  __syncthreads();
  for (int b = threadIdx.x; b < NBK; b += BS)
    if (hist[b]) atomicAdd(&gh[b], hist[b]);
}

__global__ __launch_bounds__(BS) void k_bscan(const int* __restrict__ gh,
                                              int* __restrict__ gboff,
                                              int* __restrict__ gcur, int NBK) {
  __shared__ int part[BS];
  int C = (NBK + BS - 1) / BS;
  int s = 0;
  for (int k = 0; k < C; ++k) {
    int idx = threadIdx.x * C + k;
    if (idx < NBK) s += gh[idx];
  }
  part[threadIdx.x] = s;
  __syncthreads();
  for (int off = 1; off < BS; off <<= 1) {
    int v = part[threadIdx.x];
    int u = (threadIdx.x >= off) ? part[threadIdx.x - off] : 0;
    __syncthreads();
    part[threadIdx.x] = v + u;
    __syncthreads();
  }
  int run = (threadIdx.x > 0) ? part[threadIdx.x - 1] : 0;
  for (int k = 0; k < C; ++k) {
    int idx = threadIdx.x * C + k;
    if (idx < NBK) {
      gboff[idx] = run;
      gcur[idx] = run;
      run += gh[idx];
    }
  }
  if (threadIdx.x == BS - 1) gboff[NBK] = run;  // == M
}

__global__ __launch_bounds__(BS) void k_bscatter(const int* __restrict__ ei,
                                                 const int* __restrict__ perminv,
                                                 int* __restrict__ gcur,
                                                 int2* __restrict__ P, int M, int NBK) {
  __shared__ int hist[NBK_MAX];
  __shared__ int excl[NBK_MAX];
  __shared__ int curs[NBK_MAX];
  __shared__ int base[NBK_MAX];
  __shared__ int part[BS];
  for (int b = threadIdx.x; b < NBK; b += BS) hist[b] = 0;
  __syncthreads();
  int e0 = blockIdx.x * EBT;
  int n = min(EBT, M - e0);
  for (int k = threadIdx.x; k < n; k += BS) {
    int pd = perminv[ei[M + e0 + k]];
    atomicAdd(&hist[pd / NPB], 1);
  }
  __syncthreads();
  int C = (NBK + BS - 1) / BS;
  int s = 0;
  for (int k = 0; k < C; ++k) {
    int idx = threadIdx.x * C + k;
    if (idx < NBK) s += hist[idx];
  }
  part[threadIdx.x] = s;
  __syncthreads();
  for (int off = 1; off < BS; off <<= 1) {
    int v = part[threadIdx.x];
    int u = (threadIdx.x >= off) ? part[threadIdx.x - off] : 0;
    __syncthreads();
    part[threadIdx.x] = v + u;
    __syncthreads();
  }
  int run = (threadIdx.x > 0) ? part[threadIdx.x - 1] : 0;
  for (int k = 0; k < C; ++k) {
    int idx = threadIdx.x * C + k;
    if (idx < NBK) {
      excl[idx] = run;
      curs[idx] = run;
      run += hist[idx];
    }
  }
  __syncthreads();
  for (int b = threadIdx.x; b < NBK; b += BS)
    base[b] = hist[b] ? atomicAdd(&gcur[b], hist[b]) : 0;
  __syncthreads();
  for (int k = threadIdx.x; k < n; k += BS) {
    int psrc = perminv[ei[e0 + k]];
    int pd = perminv[ei[M + e0 + k]];
    int b = pd / NPB;
    int pos = atomicAdd(&curs[b], 1);
    int gpos = base[b] + (pos - excl[b]);
    P[gpos] = make_int2(psrc, pd);
  }
}

// per-bucket LDS counting sort -> row_ptr (q-space) + srt (holds permuted src)
__global__ __launch_bounds__(BS) void k_bfinal(const int2* __restrict__ P,
                                               const int* __restrict__ gboff,
                                               int* __restrict__ row_ptr,
                                               int* __restrict__ srt, int T, int M,
                                               int NBK) {
  __shared__ int cnt[NPB];
  __shared__ int lsrt[CAP];
  __shared__ int part[BS];
  int b = blockIdx.x;
  int d0 = b * NPB;
  int nodesHere = min(NPB, T - d0);
  int p0 = gboff[b], p1 = gboff[b + 1];
  int nE = p1 - p0;
  for (int j = threadIdx.x; j < NPB; j += BS) cnt[j] = 0;
  __syncthreads();
  for (int j = threadIdx.x; j < nE; j += BS) {
    int2 p = P[p0 + j];
    atomicAdd(&cnt[p.y - d0], 1);
  }
  __syncthreads();
  const int CN = NPB / BS;  // 8
  int s = 0;
#pragma unroll
  for (int k = 0; k < CN; ++k) s += cnt[threadIdx.x * CN + k];
  part[threadIdx.x] = s;
  __syncthreads();
  for (int off = 1; off < BS; off <<= 1) {
    int v = part[threadIdx.x];
    int u = (threadIdx.x >= off) ? part[threadIdx.x - off] : 0;
    __syncthreads();
    part[threadIdx.x] = v + u;
    __syncthreads();
  }
  int run = (threadIdx.x > 0) ? part[threadIdx.x - 1] : 0;
#pragma unroll
  for (int k = 0; k < CN; ++k) {
    int idx = threadIdx.x * CN + k;
    int c = cnt[idx];
    cnt[idx] = run;
    if (idx < nodesHere) row_ptr[d0 + idx] = p0 + run;
    run += c;
  }
  if (b == NBK - 1 && threadIdx.x == 0) row_ptr[T] = M;
  __syncthreads();
  if (nE <= CAP) {
    for (int j = threadIdx.x; j < nE; j += BS) {
      int2 p = P[p0 + j];
      int pos = atomicAdd(&cnt[p.y - d0], 1);
      lsrt[pos] = p.x;
    }
    __syncthreads();
    for (int j = threadIdx.x; j < nE; j += BS) srt[p0 + j] = lsrt[j];
  } else {  // statistically unreachable fallback
    for (int j = threadIdx.x; j < nE; j += BS) {
      int2 p = P[p0 + j];
      int pos = atomicAdd(&cnt[p.y - d0], 1);
      srt[p0 + pos] = p.x;
    }
  }
}

// ---------------- math kernels ----------------

__global__ void k_prep_e(const float* __restrict__ ec, const float* __restrict__ cnt,
                         float* __restrict__ msg, float* __restrict__ oec, int E) {
  int i = blockIdx.x * BS + threadIdx.x;
  if (i >= E) return;
  float c = cnt[i], v = ec[i];
  msg[i] = v / c;
  oec[i] = (c > 0.0f) ? 0.0f : v;
}

// step 1 in ORIGINAL order; scatter-write into permuted tri4p[perminv[i]]
__global__ void k_step1pack(const float* __restrict__ msg,
                            const float* __restrict__ t12, const float* __restrict__ t13,
                            const float* __restrict__ t23,
                            const int* __restrict__ c12, const int* __restrict__ c13,
                            const int* __restrict__ c23,
                            const int* __restrict__ deg,
                            const int* __restrict__ perminv,
                            float4* __restrict__ tri4p, int T) {
  int i = blockIdx.x * BS + threadIdx.x;
  if (i >= T) return;
  int a = c12[i], b = c13[i], c = c23[i];
  float4 v;
  v.x = t12[i] + msg[a];
  v.y = t13[i] + msg[b];
  v.z = t23[i] + msg[c];
  v.w = rsqrtf((float)deg[i] + 1.0f);
  tri4p[perminv[i]] = v;
}

// edge-parallel gather: EV[e] = src[srt[e]]  (throughput-regime line fills)
__global__ __launch_bounds__(BS) void k_gather(const int* __restrict__ srt,
                                               const float4* __restrict__ src,
                                               float4* __restrict__ EV, int M) {
  int t = blockIdx.x * BS + threadIdx.x;
  int half = (M + 1) >> 1;
  if (t >= half) return;
  int t2 = t + half;
  int s0 = srt[t];
  int s1 = (t2 < M) ? srt[t2] : s0;
  float4 v0 = src[s0];
  float4 v1 = src[s1];
  EV[t] = v0;
  if (t2 < M) EV[t2] = v1;
}

// layer-1 aggregate in q-space (uniform degree within a wave -> no divergence waste)
__global__ __launch_bounds__(BS) void k_agg1c(const int* __restrict__ row_ptr,
                                              const float4* __restrict__ EV,
                                              const float4* __restrict__ tri4p,
                                              float4* __restrict__ G4p, int T) {
  int i = blockIdx.x * BS + threadIdx.x;
  if (i >= T) return;
  int r0 = row_ptr[i], r1 = row_ptr[i + 1];
  float4 ts = tri4p[i];
  float di = ts.w;
  float d2 = di * di;
  float ax = ts.x * d2, ay = ts.y * d2, az = ts.z * d2;
  int e = r0;
  float4 g;
  if (e < r1) g = EV[e];
  while (e < r1) {
    int en = e + 1;
    float4 gn = g;
    if (en < r1) gn = EV[en];
    float w = g.w * di;
    ax = fmaf(g.x, w, ax);
    ay = fmaf(g.y, w, ay);
    az = fmaf(g.z, w, az);
    g = gn;
    e = en;
  }
  float4 o;
  o.x = ax; o.y = ay; o.z = az; o.w = di;
  G4p[i] = o;
}

// fused layer2 + head in q-space; emits deltas only (dl4[q]).
// Degree-uniform waves: edge-loop trips == deg (~2 avg) vs E[max64 Poisson(2)]~7.
__global__ __launch_bounds__(BS, 4) void k_l2head(
    const int* __restrict__ row_ptr, const float4* __restrict__ EV,
    const float4* __restrict__ G4p,
    const float* __restrict__ W1, const float* __restrict__ b1,
    const float* __restrict__ W2, const float* __restrict__ b2,
    const float* __restrict__ Wout, const float* __restrict__ bout,
    float4* __restrict__ dl4, int T) {
  int i = blockIdx.x * BS + threadIdx.x;
  if (i >= T) return;
  int r0 = row_ptr[i], r1 = row_ptr[i + 1];
  float4 gi = G4p[i];
  float di = gi.w;
  float d2 = di * di;

  float acc[HID];
#pragma unroll
  for (int h = 0; h < HID; ++h) {
    float v = fmaf(gi.x, W1[h], fmaf(gi.y, W1[HID + h], fmaf(gi.z, W1[2 * HID + h], b1[h])));
    acc[h] = fmaxf(v, 0.0f) * d2;  // self-loop term
  }
  int e = r0;
  float4 g;
  if (e < r1) g = EV[e];
  while (e < r1) {
    int en = e + 1;
    float4 gn = g;
    if (en < r1) gn = EV[en];
    float w = g.w * di;
#pragma unroll
    for (int h = 0; h < HID; ++h) {
      float v = fmaf(g.x, W1[h], fmaf(g.y, W1[HID + h], fmaf(g.z, W1[2 * HID + h], b1[h])));
      acc[h] = fmaf(fmaxf(v, 0.0f), w, acc[h]);
    }
    g = gn;
    e = en;
  }

  // z = acc @ W2 + b2 in 4 chunks of 8; head folded per chunk
  float d0 = bout[0], d1 = bout[1], dd2 = bout[2];
#pragma unroll
  for (int cz = 0; cz < HID / 8; ++cz) {
    float z[8];
#pragma unroll
    for (int j = 0; j < 8; ++j) z[j] = b2[cz * 8 + j];
#pragma unroll
    for (int h = 0; h < HID; ++h) {
      float a = acc[h];
#pragma unroll
      for (int j = 0; j < 8; ++j) z[j] = fmaf(a, W2[h * HID + cz * 8 + j], z[j]);
    }
#pragma unroll
    for (int j = 0; j < 8; ++j) {
      float v = fmaxf(z[j], 0.0f);
      int hp = cz * 8 + j;
      d0 = fmaf(v, Wout[hp * 3 + 0], d0);
      d1 = fmaf(v, Wout[hp * 3 + 1], d1);
      dd2 = fmaf(v, Wout[hp * 3 + 2], dd2);
    }
  }
  float4 o;
  o.x = d0; o.y = d1; o.z = dd2; o.w = 0.0f;
  dl4[i] = o;
}

// un-permute deltas; write t-outputs; scatter-add deltas into oec.
// All index/t/msg reads sequential; one random 16B gather (dl4) per node.
__global__ __launch_bounds__(BS) void k_unperm(
    const float4* __restrict__ dl4, const int* __restrict__ perminv,
    const float* __restrict__ msg,
    const float* __restrict__ t12, const float* __restrict__ t13,
    const float* __restrict__ t23,
    const int* __restrict__ c12, const int* __restrict__ c13,
    const int* __restrict__ c23,
    float* __restrict__ o12, float* __restrict__ o13, float* __restrict__ o23,
    float* __restrict__ oec, int T) {
  int i = blockIdx.x * BS + threadIdx.x;
  if (i >= T) return;
  float4 dl = dl4[perminv[i]];
  int a = c12[i], b = c13[i], c = c23[i];
  o12[i] = t12[i] + msg[a] - dl.x;
  o13[i] = t13[i] + msg[b] - dl.y;
  o23[i] = t23[i] + msg[c] - dl.z;
  unsafeAtomicAdd(&oec[a], dl.x);
  unsafeAtomicAdd(&oec[b], dl.y);
  unsafeAtomicAdd(&oec[c], dl.z);
}

// ---------------- launch ----------------

extern "C" void kernel_launch(void* const* d_in, const int* in_sizes, int n_in,
                              void* d_out, int out_size, void* d_ws, size_t ws_size,
                              hipStream_t stream) {
  const float* ec  = (const float*)d_in[0];
  const float* t12 = (const float*)d_in[1];
  const float* t13 = (const float*)d_in[2];
  const float* t23 = (const float*)d_in[3];
  const int* c12   = (const int*)d_in[4];
  const int* c13   = (const int*)d_in[5];
  const int* c23   = (const int*)d_in[6];
  const float* cnt = (const float*)d_in[7];
  const int* ei    = (const int*)d_in[8];
  const float* W1  = (const float*)d_in[9];
  const float* b1  = (const float*)d_in[10];
  const float* W2  = (const float*)d_in[11];
  const float* b2  = (const float*)d_in[12];
  const float* Wout = (const float*)d_in[13];
  const float* bout = (const float*)d_in[14];

  const int E = in_sizes[0];
  const int T = in_sizes[1];
  const int M = in_sizes[8] / 2;
  const int NBK = (T + NPB - 1) / NPB;  // 977 for T=2M

  float* oec = (float*)d_out;
  float* o12 = oec + E;
  float* o13 = o12 + T;
  float* o23 = o13 + T;

  // workspace (~172 MB):
  // tri4p[4T] | G4p[4T] | EV[4M] | srt[M] | rptr[T+1] | msg[E] | deg[T] | perminv[T]
  //   | dh[16] | dcur[16] | gh[NBK] | gboff[NBK+1] | gcur[NBK]
  // P (8B x M) aliases EV (dead before first k_gather); dl4 aliases tri4p
  // (tri4p dead after k_agg1c; k_l2head no longer reads it).
  float4* tri4p = (float4*)d_ws;
  float4* G4p   = tri4p + T;
  float4* EV    = G4p + T;
  int*    srt   = (int*)(EV + M);
  int*    rptr  = srt + M;
  float*  msg   = (float*)(rptr + (T + 1));
  int*    deg   = (int*)(msg + E);
  int*    pinv  = deg + T;
  int*    dh    = pinv + T;
  int*    dcur  = dh + 16;
  int*    gh    = dcur + 16;
  int*    gboff = gh + NBK;
  int*    gcur  = gboff + (NBK + 1);
  int2*   P     = (int2*)EV;     // aliases EV
  float4* dl4   = tri4p;         // aliases tri4p

  auto blocks = [](long n) { return (int)((n + BS - 1) / BS); };
  const int tiles = (M + EBT - 1) / EBT;

  // degrees + degree-sorted permutation
  hipMemsetAsync(deg, 0, (size_t)T * sizeof(int), stream);
  hipMemsetAsync(dh, 0, 16 * sizeof(int), stream);
  hipMemsetAsync(gh, 0, (size_t)NBK * sizeof(int), stream);
  k_count<<<blocks(M), BS, 0, stream>>>(ei, deg, M);
  k_dhist16<<<blocks(T), BS, 0, stream>>>(deg, dh, T);
  k_dscan16<<<1, 64, 0, stream>>>(dh, dcur);
  k_dperm<<<blocks(T), BS, 0, stream>>>(deg, dcur, pinv, T);

  // bucketed counting sort by permuted dst -> q-space row_ptr + srt(=permuted src)
  k_bhist<<<tiles, BS, 0, stream>>>(ei, pinv, gh, M, NBK);
  k_bscan<<<1, BS, 0, stream>>>(gh, gboff, gcur, NBK);
  k_bscatter<<<tiles, BS, 0, stream>>>(ei, pinv, gcur, P, M, NBK);
  k_bfinal<<<NBK, BS, 0, stream>>>(P, gboff, rptr, srt, T, M, NBK);

  // per-edge prep, then step-1 pack scattered into q-space
  k_prep_e<<<blocks(E), BS, 0, stream>>>(ec, cnt, msg, oec, E);
  k_step1pack<<<blocks(T), BS, 0, stream>>>(msg, t12, t13, t23, c12, c13, c23,
                                            deg, pinv, tri4p, T);

  // layer 1: throughput gather, then degree-uniform aggregate
  k_gather<<<blocks((M + 1) / 2), BS, 0, stream>>>(srt, tri4p, EV, M);
  k_agg1c<<<blocks(T), BS, 0, stream>>>(rptr, EV, tri4p, G4p, T);

  // layer 2: throughput gather, fused layer2+head (deltas only), un-permute
  k_gather<<<blocks((M + 1) / 2), BS, 0, stream>>>(srt, G4p, EV, M);
  k_l2head<<<blocks(T), BS, 0, stream>>>(rptr, EV, G4p,
                                         W1, b1, W2, b2, Wout, bout, dl4, T);
  k_unperm<<<blocks(T), BS, 0, stream>>>(dl4, pinv, msg, t12, t13, t23,
                                         c12, c13, c23, o12, o13, o23, oec, T);
}